// Round 5
// baseline (203.495 us; speedup 1.0000x reference)
//
#include <hip/hip_runtime.h>
#include <hip/hip_fp16.h>

#define NB 8
#define NS 1024
#define NH 8
#define NBLK 512
#define NTHR 256

// ---------------------------------------------------------------------------
// Quantum layer collapsed analytically: with c_j = cos(x_j + th_j),
//   meas[0]    = c1*c2*...*c7
//   meas[w>=1] = c0*c1*...*cw
// (CNOT chain = basis permutation; E[(-1)^XOR of independent bits] = product
//  of per-bit expectations.)  q = meas[0:3]/8, k = meas[3:6], v = meas[6:8];
// scores in [-0.375,0.375] -> softmax needs no max subtraction.
// Verified vs np reference in R3/R4.
// ---------------------------------------------------------------------------

// ws layout (floats):
#define Q4_OFF  0                              // float4[64*1024] (q0,q1,q2,_)/8
#define KV4_OFF (NB * NH * NS)                 // float4[64*1024] (k0,k1,k2,v0)
#define V1_OFF  (2 * NB * NH * NS * 4)         // float[64*1024]  v1
#define ATT_OFF (V1_OFF + NB * NH * NS)        // float[8192*16]
#define WS_FLOATS (ATT_OFF + NB * NS * 16)     // = 720896 floats (2.75 MB)
#define CTR_BYTES ((size_t)WS_FLOATS * 4)      // multiple of 256; 2 counters here

static __device__ __forceinline__ void grid_barrier(unsigned* ctr) {
    __syncthreads();                 // drains block's vmem (L1 is write-through)
    if (threadIdx.x == 0) {
        __threadfence();             // agent release: L2 writeback
        __hip_atomic_fetch_add(ctr, 1u, __ATOMIC_RELEASE, __HIP_MEMORY_SCOPE_AGENT);
        while (__hip_atomic_load(ctr, __ATOMIC_ACQUIRE, __HIP_MEMORY_SCOPE_AGENT)
               < (unsigned)NBLK) {}
        __threadfence();             // agent acquire: L1/L2 invalidate
    }
    __syncthreads();                 // whole block sees post-barrier state
}

__global__ __launch_bounds__(NTHR, 2) void mono_kernel(
        const float* __restrict__ x, const float* __restrict__ theta,
        const float* __restrict__ W, const float* __restrict__ bias,
        float4* __restrict__ q4, float4* __restrict__ kv4,
        float* __restrict__ v1g, float* __restrict__ att,
        unsigned* __restrict__ ctr, float* __restrict__ out) {
    __shared__ float4 kvl[NS];            // 16 KB (aliased by proj phase)
    __shared__ float  v1l[NS];            //  4 KB
    __shared__ float  redS[4][128];       //  2 KB
    __shared__ float  redA[4][128];
    __shared__ float  redB[4][128];

    const int tid = threadIdx.x;

    // ---------------- phase 1: measurements -> ws ----------------
    {
        int gid = blockIdx.x * NTHR + tid;
        if (gid < NB * NS * NH) {
            int h = gid & 7, bs = gid >> 3;
            int s = bs & (NS - 1), b = bs >> 10;
            float th[8];
#pragma unroll
            for (int j = 0; j < 8; ++j) th[j] = theta[j];
            const float4* xp = (const float4*)(x + (((size_t)bs) << 6) + h * 8);
            float4 lo = xp[0], hi = xp[1];
            float c0 = __cosf(lo.x + th[0]);
            float c1 = __cosf(lo.y + th[1]);
            float c2 = __cosf(lo.z + th[2]);
            float c3 = __cosf(lo.w + th[3]);
            float c4 = __cosf(hi.x + th[4]);
            float c5 = __cosf(hi.y + th[5]);
            float c6 = __cosf(hi.z + th[6]);
            float c7 = __cosf(hi.w + th[7]);
            float m1 = c0 * c1;
            float m2 = m1 * c2;
            float m3 = m2 * c3;
            float m4 = m3 * c4;
            float m5 = m4 * c5;
            float m6 = m5 * c6;
            float m7 = m6 * c7;
            float m0 = ((c1 * c2) * (c3 * c4)) * ((c5 * c6) * c7);
            int o = (b * NH + h) * NS + s;
            q4[o]  = make_float4(m0 * 0.125f, m1 * 0.125f, m2 * 0.125f, 0.f);
            kv4[o] = make_float4(m3, m4, m5, m6);
            v1g[o] = m7;
        }
    }

    grid_barrier(ctr);

    // ---------------- phase 2: attention ----------------
    // block = (bh, chunk of 128 s); thread = (slice = tid>>6, ja = tid&63)
    // owning s_a = s0+ja and s_b = s0+64+ja; each loops 256 t of its slice.
    {
        const int bh = blockIdx.x >> 3;
        const int chunk = blockIdx.x & 7;
        const int s0 = chunk * 128;

        const float4* kvp = kv4 + (size_t)bh * NS;
        const float*  v1p = v1g + (size_t)bh * NS;
        for (int t = tid; t < NS; t += NTHR) { kvl[t] = kvp[t]; v1l[t] = v1p[t]; }
        __syncthreads();

        const int ja = tid & 63;
        const int slice = tid >> 6;                     // 0..3
        float4 qa = q4[(size_t)bh * NS + s0 + ja];
        float4 qb = q4[(size_t)bh * NS + s0 + 64 + ja];

        float sa = 0.f, a0a = 0.f, a1a = 0.f;
        float sb = 0.f, a0b = 0.f, a1b = 0.f;
        const int t0 = slice * 256;
#pragma unroll 8
        for (int i = 0; i < 256; ++i) {
            int t = t0 + i;
            float4 kv = kvl[t];                          // wave-uniform broadcast
            float v1 = v1l[t];
            float ea = __expf(fmaf(qa.x, kv.x, fmaf(qa.y, kv.y, qa.z * kv.z)));
            float eb = __expf(fmaf(qb.x, kv.x, fmaf(qb.y, kv.y, qb.z * kv.z)));
            sa += ea;  a0a = fmaf(ea, kv.w, a0a);  a1a = fmaf(ea, v1, a1a);
            sb += eb;  a0b = fmaf(eb, kv.w, a0b);  a1b = fmaf(eb, v1, a1b);
        }
        redS[slice][ja] = sa;  redS[slice][64 + ja] = sb;
        redA[slice][ja] = a0a; redA[slice][64 + ja] = a0b;
        redB[slice][ja] = a1a; redB[slice][64 + ja] = a1b;
        __syncthreads();

        if (tid < 128) {
            float S = redS[0][tid] + redS[1][tid] + redS[2][tid] + redS[3][tid];
            float A = redA[0][tid] + redA[1][tid] + redA[2][tid] + redA[3][tid];
            float B = redB[0][tid] + redB[1][tid] + redB[2][tid] + redB[3][tid];
            float inv = 1.0f / S;
            int b = bh >> 3, h = bh & 7;
            int s = s0 + tid;
            float* o = att + ((size_t)(b * NS + s) * 16) + h * 2;
            o[0] = A * inv;
            o[1] = B * inv;
        }
    }

    grid_barrier(ctr + 1);

    // ---------------- phase 3: projection (16 -> 64) ----------------
    {
        float* WtL   = (float*)kvl;          // 16*65 = 1040 floats (padded rows)
        float* biasL = WtL + 1040;           // 64
        float* rowsL = WtL + 1104;           // 256 (16 rows x 16)
        const int rbase = blockIdx.x * 16;   // 512*16 = 8192 (b,s) rows

        for (int i = tid; i < 1024; i += NTHR)
            WtL[(i & 15) * 65 + (i >> 4)] = W[i];        // Wt[j][e] = W[e*16+j]
        if (tid < 64) biasL[tid] = bias[tid];
        if (tid < 256) rowsL[tid] = att[(size_t)rbase * 16 + tid];
        __syncthreads();

        const int e = tid & 63, rr = tid >> 6;
#pragma unroll
        for (int p = 0; p < 4; ++p) {
            int row = p * 4 + rr;
            float acc = biasL[e];
#pragma unroll
            for (int j = 0; j < 16; ++j)
                acc = fmaf(rowsL[row * 16 + j], WtL[j * 65 + e], acc);
            out[(((size_t)(rbase + row)) << 6) + e] = acc;
        }
    }
}

// ---------------------------------------------------------------------------
// Fallback (R3, proven): fully fused, no workspace. Used only if ws too small.
// ---------------------------------------------------------------------------
#define NPAD 1028
#define SPB 32
__global__ __launch_bounds__(256) void fused_kernel(const float* __restrict__ x,
                                                    const float* __restrict__ theta,
                                                    const float* __restrict__ W,
                                                    const float* __restrict__ bias,
                                                    float* __restrict__ out) {
    __shared__ __half2 kvA[NH][NPAD];
    __shared__ __half2 kvB[NH][NPAD];
    __shared__ __half  kvC[NH][NPAD];
    __shared__ float   attl[SPB][17];
    __shared__ float   Wt[16][64];
    __shared__ float   bl[64];

    const int tid = threadIdx.x;
    const int b = blockIdx.x >> 5;
    const int chunk = blockIdx.x & 31;

    float th[8];
#pragma unroll
    for (int j = 0; j < 8; ++j) th[j] = theta[j];

    for (int i = tid; i < 1024; i += 256) Wt[i & 15][i >> 4] = W[i];
    if (tid < 64) bl[tid] = bias[tid];

    for (int i = 0; i < 32; ++i) {
        int r = tid + (i << 8);
        int h = r & 7, t = r >> 3;
        const float4* xp = (const float4*)(x + (((size_t)(b * NS + t)) << 6) + h * 8);
        float4 lo = xp[0], hi = xp[1];
        float c0 = __cosf(lo.x + th[0]);
        float c1 = __cosf(lo.y + th[1]);
        float c2 = __cosf(lo.z + th[2]);
        float c3 = __cosf(lo.w + th[3]);
        float c4 = __cosf(hi.x + th[4]);
        float c5 = __cosf(hi.y + th[5]);
        float c6 = __cosf(hi.z + th[6]);
        float c7 = __cosf(hi.w + th[7]);
        float m3 = ((c0 * c1) * c2) * c3;
        float m4 = m3 * c4;
        float m5 = m4 * c5;
        float m6 = m5 * c6;
        float m7 = m6 * c7;
        kvA[h][t] = __floats2half2_rn(m3, m4);
        kvB[h][t] = __floats2half2_rn(m5, m6);
        kvC[h][t] = __float2half_rn(m7);
    }
    __syncthreads();

    {
        const int h = tid >> 5;
        const int sl = tid & 31;
        const int sg = chunk * SPB + sl;
        const float4* xp = (const float4*)(x + (((size_t)(b * NS + sg)) << 6) + h * 8);
        float4 lo = xp[0], hi = xp[1];
        float c0 = __cosf(lo.x + th[0]);
        float c1 = __cosf(lo.y + th[1]);
        float c2 = __cosf(lo.z + th[2]);
        float c3 = __cosf(lo.w + th[3]);
        float c4 = __cosf(hi.x + th[4]);
        float c5 = __cosf(hi.y + th[5]);
        float c6 = __cosf(hi.z + th[6]);
        float c7 = __cosf(hi.w + th[7]);
        float m1 = c0 * c1;
        float m2 = m1 * c2;
        float m0 = ((c1 * c2) * (c3 * c4)) * ((c5 * c6) * c7);
        float q0 = m0 * 0.125f, q1 = m1 * 0.125f, q2 = m2 * 0.125f;

        float sum = 0.f, a0 = 0.f, a1 = 0.f;
#pragma unroll 4
        for (int t = 0; t < NS; ++t) {
            float2 kk = __half22float2(kvA[h][t]);
            float2 kv = __half22float2(kvB[h][t]);
            float v1 = __half2float(kvC[h][t]);
            float sc = q0 * kk.x + q1 * kk.y + q2 * kv.x;
            float e = __expf(sc);
            sum += e;
            a0 += e * kv.y;
            a1 += e * v1;
        }
        float inv = 1.0f / sum;
        attl[sl][h * 2] = a0 * inv;
        attl[sl][h * 2 + 1] = a1 * inv;
    }
    __syncthreads();

    {
        const int e = tid & 63;
        const int rr = tid >> 6;
#pragma unroll
        for (int i = 0; i < 8; ++i) {
            int sl = rr * 8 + i;
            float acc = bl[e];
#pragma unroll
            for (int j = 0; j < 16; ++j)
                acc += attl[sl][j] * Wt[j][e];
            int sg = chunk * SPB + sl;
            out[(((size_t)(b * NS + sg)) << 6) + e] = acc;
        }
    }
}

extern "C" void kernel_launch(void* const* d_in, const int* in_sizes, int n_in,
                              void* d_out, int out_size, void* d_ws, size_t ws_size,
                              hipStream_t stream) {
    const float* x     = (const float*)d_in[0];
    const float* theta = (const float*)d_in[1];
    const float* W     = (const float*)d_in[2];
    const float* bias  = (const float*)d_in[3];
    float* out = (float*)d_out;

    if (ws_size >= CTR_BYTES + 64) {
        float*    wsf = (float*)d_ws;
        float4*   q4  = (float4*)wsf + Q4_OFF;
        float4*   kv4 = (float4*)wsf + KV4_OFF;
        float*    v1  = wsf + V1_OFF;
        float*    att = wsf + ATT_OFF;
        unsigned* ctr = (unsigned*)((char*)d_ws + CTR_BYTES);

        hipMemsetAsync(ctr, 0, 64, stream);
        mono_kernel<<<dim3(NBLK), dim3(NTHR), 0, stream>>>(x, theta, W, bias,
                                                           q4, kv4, v1, att, ctr, out);
    } else {
        fused_kernel<<<dim3(NB * (NS / SPB)), dim3(256), 0, stream>>>(x, theta, W, bias, out);
    }
}

// Round 6
// 81.964 us; speedup vs baseline: 2.4827x; 2.4827x over previous
//
#include <hip/hip_runtime.h>
#include <hip/hip_fp16.h>

#define NB 8
#define NS 1024
#define NH 8

typedef float f2 __attribute__((ext_vector_type(2)));

// ---------------------------------------------------------------------------
// Quantum layer collapsed analytically: with c_j = cos(x_j + th_j),
//   meas[0]    = c1*c2*...*c7
//   meas[w>=1] = c0*c1*...*cw
// (CNOT chain = basis permutation; E[(-1)^XOR of independent bits] = product
//  of per-bit expectations.)  q = meas[0:3]/8, k = meas[3:6], v = meas[6:8];
// scores in [-0.375,0.375] -> softmax needs no max subtraction.
// Verified vs np reference R3/R4.
//
// R5 lesson: spin-based grid barriers (agent-scope acquire in loop) cost
// ~65 us each on gfx950 — kernel boundaries are far cheaper. 2-kernel shape.
// ---------------------------------------------------------------------------

// K1: block = (bh = blockIdx>>3, chunk = blockIdx&7 -> 128 s-values).
// Stage kv f32 for all 1024 t of this bh into LDS (computed from x directly),
// then each thread owns 2 s and 1/4 of the t-range; packed-f32 inner loop;
// LDS reduction over the 4 t-slices; write att rows.
__global__ __launch_bounds__(256, 2) void attn_fused(
        const float* __restrict__ x, const float* __restrict__ theta,
        float* __restrict__ att) {
    __shared__ float4 kvl[NS];            // (k0,k1,k2,v0) 16 KB
    __shared__ float  v1l[NS];            //  4 KB
    __shared__ float  redS[4][128];       //  2 KB x3
    __shared__ float  redA[4][128];
    __shared__ float  redB[4][128];

    const int tid = threadIdx.x;
    const int bh = blockIdx.x >> 3;
    const int chunk = blockIdx.x & 7;
    const int b = bh >> 3, h = bh & 7;
    const int s0 = chunk * 128;

    float th[8];
#pragma unroll
    for (int j = 0; j < 8; ++j) th[j] = theta[j];

    // ---- stage kv for all 1024 t (strided x reads, L2-resident) ----
#pragma unroll
    for (int i = 0; i < 4; ++i) {
        int t = tid + i * 256;
        const float4* xp = (const float4*)(x + (((size_t)(b * NS + t)) << 6) + h * 8);
        float4 lo = xp[0], hi = xp[1];
        float c0 = __cosf(lo.x + th[0]);
        float c1 = __cosf(lo.y + th[1]);
        float c2 = __cosf(lo.z + th[2]);
        float c3 = __cosf(lo.w + th[3]);
        float c4 = __cosf(hi.x + th[4]);
        float c5 = __cosf(hi.y + th[5]);
        float c6 = __cosf(hi.z + th[6]);
        float c7 = __cosf(hi.w + th[7]);
        float m3 = ((c0 * c1) * c2) * c3;
        float m4 = m3 * c4;
        float m5 = m4 * c5;
        float m6 = m5 * c6;
        kvl[t] = make_float4(m3, m4, m5, m6);
        v1l[t] = m6 * c7;
    }

    // ---- q for this thread's two s-values (recompute; 16 cos) ----
    const int ja = tid & 63;
    const int slice = tid >> 6;
    f2 qx, qy, qz;
#pragma unroll
    for (int i = 0; i < 2; ++i) {
        int s = s0 + ja + i * 64;
        const float4* xp = (const float4*)(x + (((size_t)(b * NS + s)) << 6) + h * 8);
        float4 lo = xp[0], hi = xp[1];
        float c0 = __cosf(lo.x + th[0]);
        float c1 = __cosf(lo.y + th[1]);
        float c2 = __cosf(lo.z + th[2]);
        float c3 = __cosf(lo.w + th[3]);
        float c4 = __cosf(hi.x + th[4]);
        float c5 = __cosf(hi.y + th[5]);
        float c6 = __cosf(hi.z + th[6]);
        float c7 = __cosf(hi.w + th[7]);
        float m1 = c0 * c1;
        float m2 = m1 * c2;
        float m0 = ((c1 * c2) * (c3 * c4)) * ((c5 * c6) * c7);
        qx[i] = m0 * 0.125f;
        qy[i] = m1 * 0.125f;
        qz[i] = m2 * 0.125f;
    }
    __syncthreads();

    // ---- inner loop: 256 t per slice, 2 s per thread, packed f32 ----
    f2 sum = {0.f, 0.f}, a0 = {0.f, 0.f}, a1 = {0.f, 0.f};
    const int t0 = slice * 256;
#pragma unroll 8
    for (int i = 0; i < 256; ++i) {
        int t = t0 + i;
        float4 kv = kvl[t];                 // wave-uniform broadcast
        float v1 = v1l[t];
        f2 d = qx * kv.x + qy * kv.y + qz * kv.z;   // v_pk_fma_f32
        f2 e = {__expf(d.x), __expf(d.y)};
        sum += e;
        a0 += e * kv.w;
        a1 += e * v1;
    }
    redS[slice][ja] = sum.x;  redS[slice][64 + ja] = sum.y;
    redA[slice][ja] = a0.x;   redA[slice][64 + ja] = a0.y;
    redB[slice][ja] = a1.x;   redB[slice][64 + ja] = a1.y;
    __syncthreads();

    if (tid < 128) {
        float S = redS[0][tid] + redS[1][tid] + redS[2][tid] + redS[3][tid];
        float A = redA[0][tid] + redA[1][tid] + redA[2][tid] + redA[3][tid];
        float B = redB[0][tid] + redB[1][tid] + redB[2][tid] + redB[3][tid];
        float inv = 1.0f / S;
        int s = s0 + tid;
        float* o = att + ((size_t)(b * NS + s) * 16) + h * 2;
        o[0] = A * inv;
        o[1] = B * inv;
    }
}

// K2: (8192,16) @ W^T + bias -> (8192,64). 512 blocks x 16 rows.
__global__ __launch_bounds__(256, 2) void proj_kernel(
        const float* __restrict__ att, const float* __restrict__ W,
        const float* __restrict__ bias, float* __restrict__ out) {
    __shared__ float WtL[16 * 65];        // Wt[j*65+e] = W[e*16+j], padded
    __shared__ float biasL[64];
    __shared__ float rowsL[16 * 16];
    const int tid = threadIdx.x;
    const int rbase = blockIdx.x * 16;

    for (int i = tid; i < 1024; i += 256)
        WtL[(i & 15) * 65 + (i >> 4)] = W[i];
    if (tid < 64) biasL[tid] = bias[tid];
    if (tid < 256) rowsL[tid] = att[(size_t)rbase * 16 + tid];
    __syncthreads();

    const int e = tid & 63, rr = tid >> 6;
#pragma unroll
    for (int p = 0; p < 4; ++p) {
        int row = p * 4 + rr;
        float acc = biasL[e];
#pragma unroll
        for (int j = 0; j < 16; ++j)
            acc = fmaf(rowsL[row * 16 + j], WtL[j * 65 + e], acc);
        out[(((size_t)(rbase + row)) << 6) + e] = acc;
    }
}

// ---------------------------------------------------------------------------
// Fallback (R3, proven): fully fused, no workspace. Used only if ws too small.
// ---------------------------------------------------------------------------
#define NPAD 1028
#define SPB 32
__global__ __launch_bounds__(256) void fused_kernel(const float* __restrict__ x,
                                                    const float* __restrict__ theta,
                                                    const float* __restrict__ W,
                                                    const float* __restrict__ bias,
                                                    float* __restrict__ out) {
    __shared__ __half2 kvA[NH][NPAD];
    __shared__ __half2 kvB[NH][NPAD];
    __shared__ __half  kvC[NH][NPAD];
    __shared__ float   attl[SPB][17];
    __shared__ float   Wt[16][64];
    __shared__ float   bl[64];

    const int tid = threadIdx.x;
    const int b = blockIdx.x >> 5;
    const int chunk = blockIdx.x & 31;

    float th[8];
#pragma unroll
    for (int j = 0; j < 8; ++j) th[j] = theta[j];

    for (int i = tid; i < 1024; i += 256) Wt[i & 15][i >> 4] = W[i];
    if (tid < 64) bl[tid] = bias[tid];

    for (int i = 0; i < 32; ++i) {
        int r = tid + (i << 8);
        int h = r & 7, t = r >> 3;
        const float4* xp = (const float4*)(x + (((size_t)(b * NS + t)) << 6) + h * 8);
        float4 lo = xp[0], hi = xp[1];
        float c0 = __cosf(lo.x + th[0]);
        float c1 = __cosf(lo.y + th[1]);
        float c2 = __cosf(lo.z + th[2]);
        float c3 = __cosf(lo.w + th[3]);
        float c4 = __cosf(hi.x + th[4]);
        float c5 = __cosf(hi.y + th[5]);
        float c6 = __cosf(hi.z + th[6]);
        float c7 = __cosf(hi.w + th[7]);
        float m3 = ((c0 * c1) * c2) * c3;
        float m4 = m3 * c4;
        float m5 = m4 * c5;
        float m6 = m5 * c6;
        float m7 = m6 * c7;
        kvA[h][t] = __floats2half2_rn(m3, m4);
        kvB[h][t] = __floats2half2_rn(m5, m6);
        kvC[h][t] = __float2half_rn(m7);
    }
    __syncthreads();

    {
        const int h = tid >> 5;
        const int sl = tid & 31;
        const int sg = chunk * SPB + sl;
        const float4* xp = (const float4*)(x + (((size_t)(b * NS + sg)) << 6) + h * 8);
        float4 lo = xp[0], hi = xp[1];
        float c0 = __cosf(lo.x + th[0]);
        float c1 = __cosf(lo.y + th[1]);
        float c2 = __cosf(lo.z + th[2]);
        float c3 = __cosf(lo.w + th[3]);
        float c4 = __cosf(hi.x + th[4]);
        float c5 = __cosf(hi.y + th[5]);
        float c6 = __cosf(hi.z + th[6]);
        float c7 = __cosf(hi.w + th[7]);
        float m1 = c0 * c1;
        float m2 = m1 * c2;
        float m0 = ((c1 * c2) * (c3 * c4)) * ((c5 * c6) * c7);
        float q0 = m0 * 0.125f, q1 = m1 * 0.125f, q2 = m2 * 0.125f;

        float sum = 0.f, a0 = 0.f, a1 = 0.f;
#pragma unroll 4
        for (int t = 0; t < NS; ++t) {
            float2 kk = __half22float2(kvA[h][t]);
            float2 kv = __half22float2(kvB[h][t]);
            float v1 = __half2float(kvC[h][t]);
            float sc = q0 * kk.x + q1 * kk.y + q2 * kv.x;
            float e = __expf(sc);
            sum += e;
            a0 += e * kv.y;
            a1 += e * v1;
        }
        float inv = 1.0f / sum;
        attl[sl][h * 2] = a0 * inv;
        attl[sl][h * 2 + 1] = a1 * inv;
    }
    __syncthreads();

    {
        const int e = tid & 63;
        const int rr = tid >> 6;
#pragma unroll
        for (int i = 0; i < 8; ++i) {
            int sl = rr * 8 + i;
            float acc = bl[e];
#pragma unroll
            for (int j = 0; j < 16; ++j)
                acc += attl[sl][j] * Wt[j][e];
            int sg = chunk * SPB + sl;
            out[(((size_t)(b * NS + sg)) << 6) + e] = acc;
        }
    }
}

extern "C" void kernel_launch(void* const* d_in, const int* in_sizes, int n_in,
                              void* d_out, int out_size, void* d_ws, size_t ws_size,
                              hipStream_t stream) {
    const float* x     = (const float*)d_in[0];
    const float* theta = (const float*)d_in[1];
    const float* W     = (const float*)d_in[2];
    const float* bias  = (const float*)d_in[3];
    float* out = (float*)d_out;

    if (ws_size >= (size_t)NB * NS * 16 * sizeof(float)) {
        float* att = (float*)d_ws;          // 8192 x 16 f32 (512 KB)
        attn_fused<<<dim3(NB * NH * 8), dim3(256), 0, stream>>>(x, theta, att);
        proj_kernel<<<dim3(NB * NS / 16), dim3(256), 0, stream>>>(att, W, bias, out);
    } else {
        fused_kernel<<<dim3(NB * (NS / SPB)), dim3(256), 0, stream>>>(x, theta, W, bias, out);
    }
}

// Round 7
// 78.446 us; speedup vs baseline: 2.5941x; 1.0448x over previous
//
#include <hip/hip_runtime.h>
#include <hip/hip_fp16.h>

#define NB 8
#define NS 1024
#define NH 8

typedef float f2 __attribute__((ext_vector_type(2)));

#if __has_builtin(__builtin_amdgcn_exp2f)
#define EXP2F(x) __builtin_amdgcn_exp2f(x)
#else
#define EXP2F(x) exp2f(x)
#endif

// ---------------------------------------------------------------------------
// Quantum layer collapsed analytically: with c_j = cos(x_j + th_j),
//   meas[0]    = c1*c2*...*c7
//   meas[w>=1] = c0*c1*...*cw
// (CNOT chain = basis permutation; E[(-1)^XOR of independent bits] = product
//  of per-bit expectations.)  q = meas[0:3]/8, k = meas[3:6], v = meas[6:8];
// scores in [-0.375,0.375] -> softmax needs no max subtraction. exp via
// exp2 with log2(e) folded into the q prescale. Verified vs np ref R3-R6.
//
// R5 lesson: no spin grid-barriers on gfx950 (~65 us each).
// R6 lesson: attention loop is LDS-pipe bound -> 4 s per thread + packed v1
//            to raise VALU:LDS ratio from ~1.3:1 to ~3.7:1.
// ---------------------------------------------------------------------------

// K1: block = (bh = blockIdx>>3, chunk = blockIdx&7 -> 128 s-values).
// Stage kv f32 for all 1024 t of this bh into LDS (from x directly); thread
// owns 4 s (2 f2 pairs) and 1/8 of t (128, in groups of 4); LDS-reduce the
// 8 t-slices; write att rows (8192 x 16).
__global__ __launch_bounds__(256, 2) void attn_fused(
        const float* __restrict__ x, const float* __restrict__ theta,
        float* __restrict__ att) {
    __shared__ float4 kvl[NS];                    // (k0,k1,k2,v0) 16 KB
    __shared__ __align__(16) float v1l[NS];       //  4 KB, read as float4
    __shared__ float redS[8][130];                //  3 x 4.06 KB
    __shared__ float redA[8][130];
    __shared__ float redB[8][130];

    const int tid = threadIdx.x;
    const int bh = blockIdx.x >> 3;
    const int chunk = blockIdx.x & 7;
    const int b = bh >> 3, h = bh & 7;
    const int s0 = chunk * 128;

    float th[8];
#pragma unroll
    for (int j = 0; j < 8; ++j) th[j] = theta[j];

    // ---- stage kv for all 1024 t ----
#pragma unroll
    for (int i = 0; i < 4; ++i) {
        int t = tid + i * 256;
        const float4* xp = (const float4*)(x + (((size_t)(b * NS + t)) << 6) + h * 8);
        float4 lo = xp[0], hi = xp[1];
        float c0 = __cosf(lo.x + th[0]);
        float c1 = __cosf(lo.y + th[1]);
        float c2 = __cosf(lo.z + th[2]);
        float c3 = __cosf(lo.w + th[3]);
        float c4 = __cosf(hi.x + th[4]);
        float c5 = __cosf(hi.y + th[5]);
        float c6 = __cosf(hi.z + th[6]);
        float c7 = __cosf(hi.w + th[7]);
        float m3 = ((c0 * c1) * c2) * c3;
        float m4 = m3 * c4;
        float m5 = m4 * c5;
        float m6 = m5 * c6;
        kvl[t] = make_float4(m3, m4, m5, m6);
        v1l[t] = m6 * c7;
    }

    // ---- q for this thread's 4 s-values (prescaled by log2e/8) ----
    const float QSC = 0.125f * 1.44269504088896f;
    const int sIdx = tid & 31;
    const int slice = tid >> 5;                   // 0..7
    f2 qx[2], qy[2], qz[2];
#pragma unroll
    for (int p = 0; p < 2; ++p)
#pragma unroll
        for (int i = 0; i < 2; ++i) {
            int s = s0 + sIdx + (p * 2 + i) * 32;
            const float4* xp = (const float4*)(x + (((size_t)(b * NS + s)) << 6) + h * 8);
            float4 lo = xp[0], hi = xp[1];
            float c0 = __cosf(lo.x + th[0]);
            float c1 = __cosf(lo.y + th[1]);
            float c2 = __cosf(lo.z + th[2]);
            float c3 = __cosf(lo.w + th[3]);
            float c4 = __cosf(hi.x + th[4]);
            float c5 = __cosf(hi.y + th[5]);
            float c6 = __cosf(hi.z + th[6]);
            float c7 = __cosf(hi.w + th[7]);
            float m1 = c0 * c1;
            float m2 = m1 * c2;
            float m0 = ((c1 * c2) * (c3 * c4)) * ((c5 * c6) * c7);
            qx[p][i] = m0 * QSC;
            qy[p][i] = m1 * QSC;
            qz[p][i] = m2 * QSC;
        }
    __syncthreads();

    // ---- inner loop: 128 t in groups of 4; 4 s per thread ----
    f2 sum[2] = {{0.f, 0.f}, {0.f, 0.f}};
    f2 A0[2]  = {{0.f, 0.f}, {0.f, 0.f}};
    f2 A1[2]  = {{0.f, 0.f}, {0.f, 0.f}};
    const int t0 = slice * 128;
    const float4* v1g4 = (const float4*)v1l;
#pragma unroll 2
    for (int g = 0; g < 32; ++g) {
        float4 v14 = v1g4[(t0 >> 2) + g];
        float4 kv0 = kvl[t0 + g * 4 + 0];
        float4 kv1 = kvl[t0 + g * 4 + 1];
        float4 kv2 = kvl[t0 + g * 4 + 2];
        float4 kv3 = kvl[t0 + g * 4 + 3];
        const float vv[4] = {v14.x, v14.y, v14.z, v14.w};
        const float4 kvs[4] = {kv0, kv1, kv2, kv3};
#pragma unroll
        for (int j = 0; j < 4; ++j) {
            float4 kv = kvs[j];
            float v1 = vv[j];
#pragma unroll
            for (int p = 0; p < 2; ++p) {
                f2 d = qx[p] * kv.x;
                d += qy[p] * kv.y;
                d += qz[p] * kv.z;
                f2 e = {EXP2F(d.x), EXP2F(d.y)};
                sum[p] += e;
                A0[p] += e * kv.w;
                A1[p] += e * v1;
            }
        }
    }

    redS[slice][sIdx]      = sum[0].x;
    redS[slice][sIdx + 32] = sum[0].y;
    redS[slice][sIdx + 64] = sum[1].x;
    redS[slice][sIdx + 96] = sum[1].y;
    redA[slice][sIdx]      = A0[0].x;
    redA[slice][sIdx + 32] = A0[0].y;
    redA[slice][sIdx + 64] = A0[1].x;
    redA[slice][sIdx + 96] = A0[1].y;
    redB[slice][sIdx]      = A1[0].x;
    redB[slice][sIdx + 32] = A1[0].y;
    redB[slice][sIdx + 64] = A1[1].x;
    redB[slice][sIdx + 96] = A1[1].y;
    __syncthreads();

    if (tid < 128) {
        float S = 0.f, A = 0.f, B = 0.f;
#pragma unroll
        for (int k = 0; k < 8; ++k) {
            S += redS[k][tid];
            A += redA[k][tid];
            B += redB[k][tid];
        }
        float inv = 1.0f / S;
        int s = s0 + tid;
        float* o = att + ((size_t)(b * NS + s) * 16) + h * 2;
        o[0] = A * inv;
        o[1] = B * inv;
    }
}

// K2: (8192,16) @ W^T + bias -> (8192,64). 512 blocks x 16 rows.
__global__ __launch_bounds__(256, 2) void proj_kernel(
        const float* __restrict__ att, const float* __restrict__ W,
        const float* __restrict__ bias, float* __restrict__ out) {
    __shared__ float WtL[16 * 65];        // Wt[j*65+e] = W[e*16+j], padded
    __shared__ float biasL[64];
    __shared__ float rowsL[16 * 16];
    const int tid = threadIdx.x;
    const int rbase = blockIdx.x * 16;

    for (int i = tid; i < 1024; i += 256)
        WtL[(i & 15) * 65 + (i >> 4)] = W[i];
    if (tid < 64) biasL[tid] = bias[tid];
    if (tid < 256) rowsL[tid] = att[(size_t)rbase * 16 + tid];
    __syncthreads();

    const int e = tid & 63, rr = tid >> 6;
#pragma unroll
    for (int p = 0; p < 4; ++p) {
        int row = p * 4 + rr;
        float acc = biasL[e];
#pragma unroll
        for (int j = 0; j < 16; ++j)
            acc = fmaf(rowsL[row * 16 + j], WtL[j * 65 + e], acc);
        out[(((size_t)(rbase + row)) << 6) + e] = acc;
    }
}

// ---------------------------------------------------------------------------
// Fallback (R3, proven): fully fused, no workspace. Used only if ws too small.
// ---------------------------------------------------------------------------
#define NPAD 1028
#define SPB 32
__global__ __launch_bounds__(256) void fused_kernel(const float* __restrict__ x,
                                                    const float* __restrict__ theta,
                                                    const float* __restrict__ W,
                                                    const float* __restrict__ bias,
                                                    float* __restrict__ out) {
    __shared__ __half2 kvA[NH][NPAD];
    __shared__ __half2 kvB[NH][NPAD];
    __shared__ __half  kvC[NH][NPAD];
    __shared__ float   attl[SPB][17];
    __shared__ float   Wt[16][64];
    __shared__ float   bl[64];

    const int tid = threadIdx.x;
    const int b = blockIdx.x >> 5;
    const int chunk = blockIdx.x & 31;

    float th[8];
#pragma unroll
    for (int j = 0; j < 8; ++j) th[j] = theta[j];

    for (int i = tid; i < 1024; i += 256) Wt[i & 15][i >> 4] = W[i];
    if (tid < 64) bl[tid] = bias[tid];

    for (int i = 0; i < 32; ++i) {
        int r = tid + (i << 8);
        int h = r & 7, t = r >> 3;
        const float4* xp = (const float4*)(x + (((size_t)(b * NS + t)) << 6) + h * 8);
        float4 lo = xp[0], hi = xp[1];
        float c0 = __cosf(lo.x + th[0]);
        float c1 = __cosf(lo.y + th[1]);
        float c2 = __cosf(lo.z + th[2]);
        float c3 = __cosf(lo.w + th[3]);
        float c4 = __cosf(hi.x + th[4]);
        float c5 = __cosf(hi.y + th[5]);
        float c6 = __cosf(hi.z + th[6]);
        float c7 = __cosf(hi.w + th[7]);
        float m3 = ((c0 * c1) * c2) * c3;
        float m4 = m3 * c4;
        float m5 = m4 * c5;
        float m6 = m5 * c6;
        float m7 = m6 * c7;
        kvA[h][t] = __floats2half2_rn(m3, m4);
        kvB[h][t] = __floats2half2_rn(m5, m6);
        kvC[h][t] = __float2half_rn(m7);
    }
    __syncthreads();

    {
        const int h = tid >> 5;
        const int sl = tid & 31;
        const int sg = chunk * SPB + sl;
        const float4* xp = (const float4*)(x + (((size_t)(b * NS + sg)) << 6) + h * 8);
        float4 lo = xp[0], hi = xp[1];
        float c0 = __cosf(lo.x + th[0]);
        float c1 = __cosf(lo.y + th[1]);
        float c2 = __cosf(lo.z + th[2]);
        float c3 = __cosf(lo.w + th[3]);
        float c4 = __cosf(hi.x + th[4]);
        float c5 = __cosf(hi.y + th[5]);
        float c6 = __cosf(hi.z + th[6]);
        float c7 = __cosf(hi.w + th[7]);
        float m1 = c0 * c1;
        float m2 = m1 * c2;
        float m0 = ((c1 * c2) * (c3 * c4)) * ((c5 * c6) * c7);
        float q0 = m0 * 0.125f, q1 = m1 * 0.125f, q2 = m2 * 0.125f;

        float sum = 0.f, a0 = 0.f, a1 = 0.f;
#pragma unroll 4
        for (int t = 0; t < NS; ++t) {
            float2 kk = __half22float2(kvA[h][t]);
            float2 kv = __half22float2(kvB[h][t]);
            float v1 = __half2float(kvC[h][t]);
            float sc = q0 * kk.x + q1 * kk.y + q2 * kv.x;
            float e = __expf(sc);
            sum += e;
            a0 += e * kv.y;
            a1 += e * v1;
        }
        float inv = 1.0f / sum;
        attl[sl][h * 2] = a0 * inv;
        attl[sl][h * 2 + 1] = a1 * inv;
    }
    __syncthreads();

    {
        const int e = tid & 63;
        const int rr = tid >> 6;
#pragma unroll
        for (int i = 0; i < 8; ++i) {
            int sl = rr * 8 + i;
            float acc = bl[e];
#pragma unroll
            for (int j = 0; j < 16; ++j)
                acc += attl[sl][j] * Wt[j][e];
            int sg = chunk * SPB + sl;
            out[(((size_t)(b * NS + sg)) << 6) + e] = acc;
        }
    }
}

extern "C" void kernel_launch(void* const* d_in, const int* in_sizes, int n_in,
                              void* d_out, int out_size, void* d_ws, size_t ws_size,
                              hipStream_t stream) {
    const float* x     = (const float*)d_in[0];
    const float* theta = (const float*)d_in[1];
    const float* W     = (const float*)d_in[2];
    const float* bias  = (const float*)d_in[3];
    float* out = (float*)d_out;

    if (ws_size >= (size_t)NB * NS * 16 * sizeof(float)) {
        float* att = (float*)d_ws;          // 8192 x 16 f32 (512 KB)
        attn_fused<<<dim3(NB * NH * 8), dim3(256), 0, stream>>>(x, theta, att);
        proj_kernel<<<dim3(NB * NS / 16), dim3(256), 0, stream>>>(att, W, bias, out);
    } else {
        fused_kernel<<<dim3(NB * (NS / SPB)), dim3(256), 0, stream>>>(x, theta, W, bias, out);
    }
}